// Round 1
// 243.567 us; speedup vs baseline: 1.0817x; 1.0817x over previous
//
#include <hip/hip_runtime.h>

// ---------------------------------------------------------------------------
// CavAttention fully fused: B=2 L=5 H=48 W=176 C=256, HEADS=8 DIM=32.
// rows = 84480. Block = 80 rows (16 groups of 5), 512 threads (8 waves),
// grid 1056. 8 waves = 2 waves/SIMD (vs 1 before) to cover pipeline latency.
// Each wave owns 32 output columns of every GEMM (acc[5][2]).
// Pipeline per block:  stage x->LDS(bf16) ; q-pass ; k-pass ; scores+softmax ;
// v-pass ; P@V in-place ; out-pass -> global fp32 (+bias).
// All GEMM B-operands (bf16 weights) stream through per-wave private LDS
// slots via global_load_lds (16B), depth-2, vmcnt(2)-pipelined, NO barriers.
// Barriers are lgkmcnt-only (vmcnt stays in flight across them).
// ---------------------------------------------------------------------------

typedef __attribute__((ext_vector_type(8))) short short8;
typedef __attribute__((ext_vector_type(4))) float f32x4;

#define SCALE_F 0.17677669529663687f

static __device__ __forceinline__ float b2f(unsigned short u) {
    union { unsigned u; float f; } x; x.u = ((unsigned)u) << 16; return x.f;
}
static __device__ __forceinline__ unsigned short f2b(float f) {
    union { float f; unsigned u; } x; x.f = f;
    unsigned u = x.u;
    return (unsigned short)((u + 0x7FFFu + ((u >> 16) & 1u)) >> 16);
}

// row r=(b,h,w,l) -> flat element offset in (B,L,H,W,C) order (x and out)
static __device__ __forceinline__ size_t row_to_xoff(int r) {
    int l = r % 5; int t = r / 5;
    int w = t % 176; t /= 176;
    int h = t % 48; int b = t / 48;
    return (size_t)(((b * 5 + l) * 48 + h) * 176 + w) * 256;
}

// swizzled LDS index for [row][256] bf16 buffers: 16B-chunk XOR (row&7)
static __device__ __forceinline__ int lidx(int r, int c) {
    return r * 256 + ((((c >> 3) ^ (r & 7)) << 3) | (c & 7));
}

static __device__ __forceinline__ void async_cp16(const unsigned short* g, unsigned short* l) {
    __builtin_amdgcn_global_load_lds(
        (__attribute__((address_space(1))) void*)(void*)g,
        (__attribute__((address_space(3))) void*)(void*)l, 16, 0, 0);
}

// lgkmcnt(0)-only barrier: LDS writes visible, vmcnt (B-chunk DMAs) unaffected
static __device__ __forceinline__ void barrier_lgkm() {
    __builtin_amdgcn_s_waitcnt(0xC07F);   // vmcnt=63(free), expcnt=7, lgkmcnt=0
    __builtin_amdgcn_s_barrier();
}

// --------------------------- prep: weights -> bf16, transposed [n][k] ------
__global__ __launch_bounds__(256) void k_prep(const float* __restrict__ wq,
                                              const float* __restrict__ wo,
                                              unsigned short* __restrict__ wqt,
                                              unsigned short* __restrict__ wot) {
    int i = blockIdx.x * 256 + threadIdx.x;      // grid covers 196608
    if (i < 196608) { int k = i / 768, n = i % 768; wqt[n * 256 + k] = f2b(wq[i]); }
    if (i < 65536)  { int k = i / 256, n = i % 256; wot[n * 256 + k] = f2b(wo[i]); }
}

// ---- B-chunk DMA: chunk C (global id 0..31): pass C>>3, kk C&7, slot C&1 ---
// chunk = this wave's 32 B-rows x 32 k (2KB). LDS layout: [n][kq] with
// kq-slot swizzle slot = kq ^ ((n>>1)&3) -> b128 frag reads are 2-way (free).
template<int C>
static __device__ __forceinline__ void issue_chunk(const unsigned short* __restrict__ wqt,
                                                   const unsigned short* __restrict__ wot,
                                                   unsigned short* __restrict__ Bw,
                                                   int n0w, int lane) {
    constexpr int p = C >> 3;
    constexpr int kk = C & 7;
    constexpr int slot = C & 1;
    const unsigned short* wbase = (p < 3) ? (wqt + p * 65536) : wot;
#pragma unroll
    for (int t = 0; t < 2; ++t) {
        int cidx = t * 64 + lane;
        int nl = cidx >> 2;                       // B-row within wave chunk (0..31)
        int kq = (cidx & 3) ^ ((nl >> 1) & 3);    // swizzled 16B sub-chunk
        const unsigned short* g = wbase + (n0w + nl) * 256 + kk * 32 + kq * 8;
        async_cp16(g, Bw + slot * 1024 + t * 512);  // dest: base + lane*16B
    }
}

// ---- one K=32 step: wait chunk C, read B-frags, refill slot, 10 MFMAs -----
template<int C>
static __device__ __forceinline__ void chunk_step(f32x4 (&acc)[5][2],
        const unsigned short* __restrict__ As, unsigned short* __restrict__ Bw,
        const unsigned short* __restrict__ wqt, const unsigned short* __restrict__ wot,
        int n0w, int lane) {
    constexpr int kk = C & 7;
    constexpr int slot = C & 1;
    constexpr int imm = (C == 31) ? 0xF70 : 0xF72;   // vmcnt(0) : vmcnt(2)
    const int ln = lane & 15, quad = lane >> 4;
    __builtin_amdgcn_s_waitcnt(imm);                 // chunk C DMA complete
    short8 b[2];
#pragma unroll
    for (int n = 0; n < 2; ++n)
        b[n] = *(const short8*)&Bw[slot * 1024 + (n * 16 + ln) * 32
                                   + ((quad ^ ((ln >> 1) & 3)) * 8)];
    __builtin_amdgcn_s_waitcnt(0xC07F);              // b in VGPRs; slot reusable
    if constexpr (C + 2 < 32) issue_chunk<C + 2>(wqt, wot, Bw, n0w, lane);
    short8 a[5];
#pragma unroll
    for (int m = 0; m < 5; ++m)
        a[m] = *(const short8*)&As[lidx(m * 16 + ln, kk * 32 + quad * 8)];
#pragma unroll
    for (int m = 0; m < 5; ++m)
#pragma unroll
        for (int n = 0; n < 2; ++n)
            acc[m][n] = __builtin_amdgcn_mfma_f32_16x16x32_bf16(a[m], b[n], acc[m][n], 0, 0, 0);
}

template<int P>
static __device__ __forceinline__ void gemm8(f32x4 (&acc)[5][2],
        const unsigned short* __restrict__ As, unsigned short* __restrict__ Bw,
        const unsigned short* __restrict__ wqt, const unsigned short* __restrict__ wot,
        int n0w, int lane) {
    chunk_step<P * 8 + 0>(acc, As, Bw, wqt, wot, n0w, lane);
    chunk_step<P * 8 + 1>(acc, As, Bw, wqt, wot, n0w, lane);
    chunk_step<P * 8 + 2>(acc, As, Bw, wqt, wot, n0w, lane);
    chunk_step<P * 8 + 3>(acc, As, Bw, wqt, wot, n0w, lane);
    chunk_step<P * 8 + 4>(acc, As, Bw, wqt, wot, n0w, lane);
    chunk_step<P * 8 + 5>(acc, As, Bw, wqt, wot, n0w, lane);
    chunk_step<P * 8 + 6>(acc, As, Bw, wqt, wot, n0w, lane);
    chunk_step<P * 8 + 7>(acc, As, Bw, wqt, wot, n0w, lane);
}

// C/D layout: col = lane&15, row = quad*4 + reg (m89/m91-verified)
static __device__ __forceinline__ void cstore(const f32x4 (&acc)[5][2],
        unsigned short* __restrict__ Ds, int n0w, int lane) {
    const int ln = lane & 15, quad = lane >> 4;
#pragma unroll
    for (int m = 0; m < 5; ++m)
#pragma unroll
        for (int n = 0; n < 2; ++n)
#pragma unroll
            for (int rg = 0; rg < 4; ++rg)
                Ds[lidx(m * 16 + quad * 4 + rg, n0w + n * 16 + ln)] = f2b(acc[m][n][rg]);
}

// --------------------------- the fused kernel ------------------------------
__global__ __launch_bounds__(512, 2) void k_fused(const float* __restrict__ x,
                                                  const int* __restrict__ mask,
                                                  const unsigned short* __restrict__ wqt,
                                                  const unsigned short* __restrict__ wot,
                                                  const float* __restrict__ bo,
                                                  float* __restrict__ out) {
    __shared__ __align__(16) unsigned short xs[80 * 256];    // 40 KB
    __shared__ __align__(16) unsigned short qs[80 * 256];    // 40 KB
    __shared__ __align__(16) unsigned short kvs[80 * 256];   // 40 KB (k, v, att)
    __shared__ __align__(16) unsigned short Bb[8 * 2048];    // 32 KB: 8 waves x 2 slots x 2KB

    const int tid = threadIdx.x;
    const int blk = blockIdx.x;
    const int rbase = blk * 80;
    const int lane = tid & 63, wv = tid >> 6;
    const int n0w = wv * 32;
    unsigned short* Bw = Bb + wv * 2048;

    // ---- stage x: 80 rows x 256, fp32 -> bf16, swizzled ----
#pragma unroll
    for (int i = 0; i < 5; ++i) {
        int u = i * 512 + tid;                    // 2560 units of 8 elems
        int r = u >> 5, cb = u & 31;
        size_t xo = row_to_xoff(rbase + r) + cb * 8;
        float4 v0 = *(const float4*)(x + xo);
        float4 v1 = *(const float4*)(x + xo + 4);
        short8 o;
        o[0] = (short)f2b(v0.x); o[1] = (short)f2b(v0.y);
        o[2] = (short)f2b(v0.z); o[3] = (short)f2b(v0.w);
        o[4] = (short)f2b(v1.x); o[5] = (short)f2b(v1.y);
        o[6] = (short)f2b(v1.z); o[7] = (short)f2b(v1.w);
        *(short8*)&xs[lidx(r, cb * 8)] = o;
    }

    // ---- mask preload for this thread's attention group ----
    const int part = tid & 3, hh = (tid >> 2) & 7, g = tid >> 5;  // g in 0..15
    int mk[5];
#pragma unroll
    for (int j = 0; j < 5; ++j) mk[j] = mask[(blk * 16 + g) * 5 + j];

    // prime the B pipeline (wave-private; no barrier needed)
    issue_chunk<0>(wqt, wot, Bw, n0w, lane);
    issue_chunk<1>(wqt, wot, Bw, n0w, lane);

    barrier_lgkm();   // xs visible

    // ---- q pass ----
    {
        f32x4 acc[5][2];
#pragma unroll
        for (int m = 0; m < 5; ++m)
#pragma unroll
            for (int n = 0; n < 2; ++n) acc[m][n] = (f32x4){0.f, 0.f, 0.f, 0.f};
        gemm8<0>(acc, xs, Bw, wqt, wot, n0w, lane);
        cstore(acc, qs, n0w, lane);
    }
    // ---- k pass ----
    {
        f32x4 acc[5][2];
#pragma unroll
        for (int m = 0; m < 5; ++m)
#pragma unroll
            for (int n = 0; n < 2; ++n) acc[m][n] = (f32x4){0.f, 0.f, 0.f, 0.f};
        gemm8<1>(acc, xs, Bw, wqt, wot, n0w, lane);
        cstore(acc, kvs, n0w, lane);
    }
    barrier_lgkm();   // q,k visible

    // ---- scores + softmax (one group per 32 threads) ----
    float pr[5][5];
    {
        const int c0 = hh * 32 + part * 8;
        float qf[5][8];
#pragma unroll
        for (int i = 0; i < 5; ++i) {
            short8 qv = *(const short8*)&qs[lidx(g * 5 + i, c0)];
#pragma unroll
            for (int d = 0; d < 8; ++d) qf[i][d] = b2f((unsigned short)qv[d]);
        }
        float s[5][5];
#pragma unroll
        for (int j = 0; j < 5; ++j) {
            short8 kv = *(const short8*)&kvs[lidx(g * 5 + j, c0)];
            float kf[8];
#pragma unroll
            for (int d = 0; d < 8; ++d) kf[d] = b2f((unsigned short)kv[d]);
#pragma unroll
            for (int i = 0; i < 5; ++i) {
                float acc = 0.f;
#pragma unroll
                for (int d = 0; d < 8; ++d) acc += qf[i][d] * kf[d];
                s[i][j] = acc;
            }
        }
#pragma unroll
        for (int i = 0; i < 5; ++i)
#pragma unroll
            for (int j = 0; j < 5; ++j) {
                s[i][j] += __shfl_xor(s[i][j], 1, 64);
                s[i][j] += __shfl_xor(s[i][j], 2, 64);
            }
#pragma unroll
        for (int i = 0; i < 5; ++i) {
            float mx = -1e30f;
#pragma unroll
            for (int j = 0; j < 5; ++j) {
                s[i][j] = mk[j] ? s[i][j] * SCALE_F : -1e30f;
                mx = fmaxf(mx, s[i][j]);
            }
            float sum = 0.f;
#pragma unroll
            for (int j = 0; j < 5; ++j) { pr[i][j] = __expf(s[i][j] - mx); sum += pr[i][j]; }
            float inv = 1.f / sum;
#pragma unroll
            for (int j = 0; j < 5; ++j) pr[i][j] *= inv;
        }
    }
    barrier_lgkm();   // all k reads done before v overwrites kvs

    // ---- v pass ----
    {
        f32x4 acc[5][2];
#pragma unroll
        for (int m = 0; m < 5; ++m)
#pragma unroll
            for (int n = 0; n < 2; ++n) acc[m][n] = (f32x4){0.f, 0.f, 0.f, 0.f};
        gemm8<2>(acc, xs, Bw, wqt, wot, n0w, lane);
        cstore(acc, kvs, n0w, lane);
    }
    barrier_lgkm();   // v visible

    // ---- P@V, att written in-place over v (same (row,col) slice ownership) --
    {
        const int c0 = hh * 32 + part * 8;
        float o[5][8];
#pragma unroll
        for (int i = 0; i < 5; ++i)
#pragma unroll
            for (int d = 0; d < 8; ++d) o[i][d] = 0.f;
#pragma unroll
        for (int j = 0; j < 5; ++j) {
            short8 vv = *(const short8*)&kvs[lidx(g * 5 + j, c0)];
            float vf[8];
#pragma unroll
            for (int d = 0; d < 8; ++d) vf[d] = b2f((unsigned short)vv[d]);
#pragma unroll
            for (int i = 0; i < 5; ++i)
#pragma unroll
                for (int d = 0; d < 8; ++d) o[i][d] += pr[i][j] * vf[d];
        }
#pragma unroll
        for (int i = 0; i < 5; ++i) {
            short8 ov;
#pragma unroll
            for (int d = 0; d < 8; ++d) ov[d] = (short)f2b(o[i][d]);
            *(short8*)&kvs[lidx(g * 5 + i, c0)] = ov;
        }
    }
    barrier_lgkm();   // att visible

    // ---- out pass: att @ Wout + b -> global fp32 scatter ----
    {
        f32x4 acc[5][2];
#pragma unroll
        for (int m = 0; m < 5; ++m)
#pragma unroll
            for (int n = 0; n < 2; ++n) acc[m][n] = (f32x4){0.f, 0.f, 0.f, 0.f};
        gemm8<3>(acc, kvs, Bw, wqt, wot, n0w, lane);
        const int ln = lane & 15, quad = lane >> 4;
        float bv[2];
#pragma unroll
        for (int n = 0; n < 2; ++n) bv[n] = bo[n0w + n * 16 + ln];
#pragma unroll
        for (int m = 0; m < 5; ++m)
#pragma unroll
            for (int rg = 0; rg < 4; ++rg) {
                int row = m * 16 + quad * 4 + rg;
                size_t off = row_to_xoff(rbase + row);
#pragma unroll
                for (int n = 0; n < 2; ++n)
                    out[off + n0w + n * 16 + ln] = acc[m][n][rg] + bv[n];
            }
    }
}

// ---------------------------------------------------------------------------
extern "C" void kernel_launch(void* const* d_in, const int* in_sizes, int n_in,
                              void* d_out, int out_size, void* d_ws, size_t ws_size,
                              hipStream_t stream) {
    const float* x   = (const float*)d_in[0];
    const int* mask  = (const int*)d_in[1];
    const float* wq  = (const float*)d_in[2];
    const float* wo  = (const float*)d_in[3];
    const float* bo  = (const float*)d_in[4];
    float* out = (float*)d_out;

    char* ws = (char*)d_ws;
    // ws: wqt bf16 [768][256] (393216 B) | wot bf16 [256][256] (131072 B)
    unsigned short* wqt = (unsigned short*)(ws);
    unsigned short* wot = (unsigned short*)(ws + 393216);

    hipLaunchKernelGGL(k_prep, dim3(768), dim3(256), 0, stream, wq, wo, wqt, wot);
    hipLaunchKernelGGL(k_fused, dim3(1056), dim3(512), 0, stream, x, mask, wqt, wot, bo, out);
}